// Round 9
// baseline (207.743 us; speedup 1.0000x reference)
//
#include <hip/hip_runtime.h>

// Problem constants (B=2,S=1024 -> T=2048; H=1024, I=512, SI=2048, E=8, TOPK=2)
#define T_TOK 2048
#define H_DIM 1024
#define I_DIM 512
#define SI_DIM 2048
#define E_NUM 8
#define NSLOT 4096  // total expert slots: exactly 2 per token

typedef __attribute__((ext_vector_type(8))) short short8;   // 8 x bf16 (4 VGPRs)
typedef __attribute__((ext_vector_type(4))) float floatx4;  // MFMA C/D

// fp32 -> bf16 round-to-nearest-even
__device__ inline unsigned short f2bf(float f) {
  unsigned u = __builtin_bit_cast(unsigned, f);
  u = (u + 0x7FFFu + ((u >> 16) & 1u)) >> 16;
  return (unsigned short)u;
}
__device__ inline float bf2f(unsigned short u) {
  return __builtin_bit_cast(float, (unsigned)u << 16);
}

// async global->LDS, 16B per lane; LDS dest = wave-uniform base + lane*16
__device__ inline void gl_lds16(const void* g, void* l) {
  __builtin_amdgcn_global_load_lds(
      (const __attribute__((address_space(1))) unsigned int*)g,
      (__attribute__((address_space(3))) unsigned int*)l, 16, 0, 0);
}

// Read one bf16x8 MFMA B-fragment from an fp32 LDS tile (32 floats/row,
// chunk-swizzled: logical 16B chunk c of row r stored at pos c^(r&7)).
// 2x ds_read_b128 + 4x v_cvt_pk_bf16_f32 (RNE, same rounding as f2bf).
__device__ __forceinline__ short8 bfrag_f32(const float* Bb, int rr, int kk) {
  float4 a0 = *(const float4*)&Bb[rr * 32 + (((2 * kk) ^ (rr & 7)) << 2)];
  float4 a1 = *(const float4*)&Bb[rr * 32 + (((2 * kk + 1) ^ (rr & 7)) << 2)];
  unsigned u0, u1, u2, u3;
  asm("v_cvt_pk_bf16_f32 %0, %1, %2" : "=v"(u0) : "v"(a0.x), "v"(a0.y));
  asm("v_cvt_pk_bf16_f32 %0, %1, %2" : "=v"(u1) : "v"(a0.z), "v"(a0.w));
  asm("v_cvt_pk_bf16_f32 %0, %1, %2" : "=v"(u2) : "v"(a1.x), "v"(a1.y));
  asm("v_cvt_pk_bf16_f32 %0, %1, %2" : "=v"(u3) : "v"(a1.z), "v"(a1.w));
  uint4 r = make_uint4(u0, u1, u2, u3);
  return __builtin_bit_cast(short8, r);
}

// ---------------------------------------------------------------------------
// Fused cast + router. Round-9: GEMMs read WEIGHTS fp32 directly (B-operand
// fp32 LDS staging + read-side cvt_pk), so the only cast left is x -> bf16.
// Removes ~176 MB of cast traffic (was the single largest attackable cost).
// Blocks [0,512): router. [512,1536): x cast (8 elems/thread, 16B stores).
// ---------------------------------------------------------------------------
__global__ __launch_bounds__(256) void cast_router(
    const float* __restrict__ x, const float* __restrict__ rw,
    const float* __restrict__ segw, unsigned short* __restrict__ xb,
    int* __restrict__ top2, float2* __restrict__ w01, float* __restrict__ sg) {
  const int bid = blockIdx.x;
  if (bid < 512) {
    // ---- router: one wave per token, fp32 logits (matches ref numerics) ----
    int t = bid * 4 + (threadIdx.x >> 6);
    int lane = threadIdx.x & 63;
    const float* xt = x + (long)t * H_DIM;
    float xv[16];
#pragma unroll
    for (int j = 0; j < 16; ++j) xv[j] = xt[j * 64 + lane];
    float dots[9];
#pragma unroll
    for (int e = 0; e < 8; ++e) {
      const float* w = rw + e * H_DIM;
      float s = 0.f;
#pragma unroll
      for (int j = 0; j < 16; ++j) s += xv[j] * w[j * 64 + lane];
      dots[e] = s;
    }
    {
      float s = 0.f;
#pragma unroll
      for (int j = 0; j < 16; ++j) s += xv[j] * segw[j * 64 + lane];
      dots[8] = s;
    }
#pragma unroll
    for (int off = 32; off > 0; off >>= 1) {
#pragma unroll
      for (int e = 0; e < 9; ++e) dots[e] += __shfl_xor(dots[e], off, 64);
    }
    if (lane == 0) {
      int e0 = 0;
      for (int e = 1; e < 8; ++e)
        if (dots[e] > dots[e0]) e0 = e;
      int e1 = (e0 == 0) ? 1 : 0;
      for (int e = 0; e < 8; ++e)
        if (e != e0 && dots[e] > dots[e1]) e1 = e;
      float p1 = expf(dots[e1] - dots[e0]);
      top2[t] = e0 | (e1 << 8);
      w01[t] = make_float2(1.f / (1.f + p1), p1 / (1.f + p1));
      sg[t] = 1.f / (1.f + expf(-dots[8]));
    }
  } else {
    // ---- x cast: 8 fp32 -> 8 bf16 (one 16B store); 262144 groups ----
    long g = (long)(bid - 512) * 256 + threadIdx.x;
    const float4* sp = (const float4*)x;
    float4 v0 = sp[g * 2];
    float4 v1 = sp[g * 2 + 1];
    uint4 u;
    u.x = (unsigned)f2bf(v0.x) | ((unsigned)f2bf(v0.y) << 16);
    u.y = (unsigned)f2bf(v0.z) | ((unsigned)f2bf(v0.w) << 16);
    u.z = (unsigned)f2bf(v1.x) | ((unsigned)f2bf(v1.y) << 16);
    u.w = (unsigned)f2bf(v1.z) | ((unsigned)f2bf(v1.w) << 16);
    ((uint4*)xb)[g] = u;
  }
}

// ---------------------------------------------------------------------------
// Router phase 2: one block per expert; block-wide scan -> compact slot list
// (global base = #assignments to experts < e) + tok_slot back-pointers.
// ---------------------------------------------------------------------------
__global__ __launch_bounds__(256) void build_lists(
    const int* __restrict__ top2, int* __restrict__ cnt, int* __restrict__ ebase,
    int* __restrict__ slot_token, int* __restrict__ tok_slot) {
  const int e = blockIdx.x;
  const int tid = threadIdx.x;
  const int lane = tid & 63, wid = tid >> 6;
  __shared__ int wsum[4], wbelow[4];
  const int base_t = tid * 8;  // 2048 / 256
  int mk[8], kk[8];
  int c = 0, below = 0;
#pragma unroll
  for (int j = 0; j < 8; ++j) {
    int p = top2[base_t + j];
    int e0 = p & 0xFF, e1 = (p >> 8) & 0xFF;
    below += (e0 < e) + (e1 < e);
    int m = 0, k = 0;
    if (e0 == e) { m = 1; k = 0; }
    else if (e1 == e) { m = 1; k = 1; }
    mk[j] = m; kk[j] = k;
    c += m;
  }
  int inc = c;
#pragma unroll
  for (int off = 1; off < 64; off <<= 1) {
    int n = __shfl_up(inc, off, 64);
    if (lane >= off) inc += n;
  }
  int bsum = below;
#pragma unroll
  for (int off = 32; off > 0; off >>= 1) bsum += __shfl_xor(bsum, off, 64);
  if (lane == 63) wsum[wid] = inc;
  if (lane == 0) wbelow[wid] = bsum;
  __syncthreads();
  int woff = 0;
#pragma unroll
  for (int i = 0; i < 4; ++i)
    if (i < wid) woff += wsum[i];
  int baseE = wbelow[0] + wbelow[1] + wbelow[2] + wbelow[3];
  int pos = baseE + woff + inc - c;
#pragma unroll
  for (int j = 0; j < 8; ++j) {
    if (mk[j]) {
      slot_token[pos] = base_t + j;
      tok_slot[2 * (base_t + j) + kk[j]] = pos;
      pos++;
    }
  }
  if (tid == 255) cnt[e] = woff + inc;
  if (tid == 0) ebase[e] = baseE;
}

// ---------------------------------------------------------------------------
// Fused SwiGLU GEMM body: act = silu(A@Bg^T)*(A@Bu^T). A bf16; Bg/Bu FP32
// (read directly from input weights — no cast pass). BM=128, BN=128, BK=32,
// 4 waves, 32 MFMA/wave-iter, r4-proven dbuf loop (1 barrier/iter).
// B staging: fp32 LDS tile [128 rows][32 floats], logical chunk c of row r
// at pos c^(r&7) (pre-swizzled global source; gl_lds16 writes linear).
// B frags convert on read via bfrag_f32 (2-way max conflict per phase).
// LDS: A 2x8KB bf16 + Bg 2x16KB + Bu 2x16KB = 80KB -> 2 blocks/CU (160KB).
// ---------------------------------------------------------------------------
template <bool GATHER>
__device__ __forceinline__ void swiglu_body(
    char* smem, int bx, int by, int e,
    const unsigned short* __restrict__ A, const float* __restrict__ Bg,
    const float* __restrict__ Bu, unsigned short* __restrict__ Out,
    const int* __restrict__ slot_token, const int* __restrict__ cnt,
    const int* __restrict__ ebase, int N, int K, long estrideB) {
  constexpr int BM = 128, BN = 128, BK = 32;
  constexpr int ATILE = BM * BK;    // 4096 ushorts (8KB)
  constexpr int BTILEF = BN * BK;   // 4096 floats (16KB)
  const int tid = threadIdx.x;
  const int lane = tid & 63;
  const int wid = tid >> 6;  // 0..3
  const int wm = wid & 1;
  const int wn = wid >> 1;
  const int m0 = by * BM;
  const int n0 = bx * BN;
  int Meff = 0, baseE = 0;
  if (GATHER) {
    Meff = cnt[e];
    if (m0 >= Meff) return;
    baseE = ebase[e];
  }
  const float* BgE = Bg + (long)e * estrideB;
  const float* BuE = Bu + (long)e * estrideB;

  unsigned short* As = (unsigned short*)smem;       // [2][4096] ushorts
  float* BgsF = (float*)(smem + 16384);             // [2][4096] floats
  float* BusF = (float*)(smem + 49152);             // [2][4096] floats

  // A staging addressing (bf16, unchanged from r4)
  const int lrow = lane >> 2;  // 16 rows / 1KB chunk
  const int lcol = (((lane & 3) ^ ((lrow >> 1) & 3)) << 4);

  const char* aP[2];
#pragma unroll
  for (int i = 0; i < 2; ++i) {
    int m = m0 + wid * 32 + i * 16 + lrow;
    long row;
    if (GATHER) {
      int mm = (m < Meff - 1) ? m : (Meff - 1);  // clamp tail to valid slot
      row = slot_token[baseE + mm];
    } else {
      row = m;
    }
    aP[i] = (const char*)A + row * (long)(K * 2) + lcol;
  }

  // B staging addressing (fp32): call i covers rows wid*32+i*8 .. +8;
  // lane l -> row +(l>>3), fetches logical chunk (l&7)^((l>>3)&7).
  const int br8 = lane >> 3;
  const int bck = (lane & 7) ^ (br8 & 7);
  const char* bgPf[4];
  const char* buPf[4];
#pragma unroll
  for (int i = 0; i < 4; ++i) {
    int n = n0 + wid * 32 + i * 8 + br8;
    bgPf[i] = (const char*)BgE + (long)n * (K * 4) + bck * 16;
    buPf[i] = (const char*)BuE + (long)n * (K * 4) + bck * 16;
  }

  floatx4 accG[4][4], accU[4][4];
  floatx4 zero = {0.f, 0.f, 0.f, 0.f};
#pragma unroll
  for (int i = 0; i < 4; ++i)
#pragma unroll
    for (int j = 0; j < 4; ++j) { accG[i][j] = zero; accU[i][j] = zero; }

  const int ar = lane & 15;
  const int aksw = (((lane >> 4) ^ ((ar >> 1) & 3)) << 3);
  const int kk = lane >> 4;

  auto stage = [&](int p, int k0) {
#pragma unroll
    for (int i = 0; i < 2; ++i)
      gl_lds16(aP[i] + (long)k0 * 2, &As[p * ATILE + (wid * 32 + i * 16) * BK]);
#pragma unroll
    for (int i = 0; i < 4; ++i) {
      gl_lds16(bgPf[i] + (long)k0 * 4, &BgsF[p * BTILEF + (wid * 32 + i * 8) * BK]);
      gl_lds16(buPf[i] + (long)k0 * 4, &BusF[p * BTILEF + (wid * 32 + i * 8) * BK]);
    }
  };

  stage(0, 0);
  const int NI = K / BK;
  for (int i = 0; i < NI; ++i) {
    __syncthreads();  // vmcnt drained before barrier -> buf[i&1] ready
    if (i + 1 < NI) stage((i + 1) & 1, (i + 1) * BK);
    const unsigned short* Ab = &As[(i & 1) * ATILE];
    const float* Gb = &BgsF[(i & 1) * BTILEF];
    const float* Ub = &BusF[(i & 1) * BTILEF];
    short8 af[4], bgf[4], buf2[4];
#pragma unroll
    for (int tm = 0; tm < 4; ++tm)
      af[tm] = *(const short8*)&Ab[(wm * 64 + tm * 16 + ar) * BK + aksw];
#pragma unroll
    for (int tn = 0; tn < 4; ++tn) {
      int rr = wn * 64 + tn * 16 + ar;
      bgf[tn] = bfrag_f32(Gb, rr, kk);
      buf2[tn] = bfrag_f32(Ub, rr, kk);
    }
#pragma unroll
    for (int tm = 0; tm < 4; ++tm)
#pragma unroll
      for (int tn = 0; tn < 4; ++tn) {
        accG[tm][tn] = __builtin_amdgcn_mfma_f32_16x16x32_bf16(af[tm], bgf[tn], accG[tm][tn], 0, 0, 0);
        accU[tm][tn] = __builtin_amdgcn_mfma_f32_16x16x32_bf16(af[tm], buf2[tn], accU[tm][tn], 0, 0, 0);
      }
  }

#pragma unroll
  for (int tm = 0; tm < 4; ++tm)
#pragma unroll
    for (int tn = 0; tn < 4; ++tn)
#pragma unroll
      for (int r = 0; r < 4; ++r) {
        int row = m0 + wm * 64 + tm * 16 + (lane >> 4) * 4 + r;
        int col = n0 + wn * 64 + tn * 16 + (lane & 15);
        if (!GATHER || row < Meff) {
          float g = accG[tm][tn][r];
          float u = accU[tm][tn][r];
          float act = g / (1.f + expf(-g)) * u;
          Out[(long)(baseE + row) * N + col] = f2bf(act);
        }
      }
}

// Fused launch (256 threads, 80KB LDS):
//   [0,256)   shared SwiGLU (16bx x 16by), Bg/Bu = shared_gate/up fp32
//   [256,768) expert SwiGLU (4bx x 16by per expert), Bg/Bu = gate_up fp32
__global__ __launch_bounds__(256, 2) void swiglu_fused(
    const unsigned short* __restrict__ xb, const float* __restrict__ sgw,
    const float* __restrict__ suw, unsigned short* __restrict__ act_s,
    const float* __restrict__ gup, unsigned short* __restrict__ act_e,
    const int* __restrict__ slot_token, const int* __restrict__ cnt,
    const int* __restrict__ ebase) {
  __shared__ __align__(16) char smem[81920];
  int bid = blockIdx.x;
  if (bid < 256) {
    swiglu_body<false>(smem, bid & 15, bid >> 4, 0, xb, sgw, suw, act_s,
                       nullptr, nullptr, nullptr, SI_DIM, H_DIM, 0);
  } else {
    int b2 = bid - 256;
    int e = b2 >> 6;
    int rem = b2 & 63;  // bx in [0,4), by in [0,16)
    swiglu_body<true>(smem, rem & 3, rem >> 2, e, xb, gup,
                      gup + (long)I_DIM * H_DIM, act_e, slot_token, cnt,
                      ebase, I_DIM, H_DIM, (long)2 * I_DIM * H_DIM);
  }
}

// ---------------------------------------------------------------------------
// Down-proj GEMM body: C = A@B^T. A bf16 (our activations); B FP32 weights
// read directly. BM=128, BN=256, BK=32, 4 waves, 32 MFMA/wave-iter,
// r4-proven dbuf loop + fp32-B staging as in swiglu_body.
// LDS: A 2x8KB + B 2x32KB fp32 = 80KB -> 2 blocks/CU.
// MODE 0: shared split-K part 0 -> OutF[row][col] = v (raw fp32)
// MODE 2: shared split-K part 1 -> OutB[row][col] = bf16(v)
// MODE 1: expert -> OutB[(baseE+row)][col] = bf16(v)
// ---------------------------------------------------------------------------
template <int MODE>
__device__ __forceinline__ void down_body(
    char* smem, int bx, int by, int e,
    const unsigned short* __restrict__ A, const float* __restrict__ B,
    float* __restrict__ OutF, unsigned short* __restrict__ OutB,
    const int* __restrict__ ebase, const int* __restrict__ cnt,
    int N, int Kstride, int kbeg, int kcnt, long estrideB) {
  constexpr int BM = 128, BN = 256, BK = 32;
  constexpr int ATILE = BM * BK;    // 4096 ushorts (8KB)
  constexpr int BTILEF = BN * BK;   // 8192 floats (32KB)
  const int tid = threadIdx.x;
  const int lane = tid & 63;
  const int wid = tid >> 6;
  const int wm = wid & 1;
  const int wn = wid >> 1;
  const int m0 = by * BM;
  const int n0 = bx * BN;
  int Meff = 0, baseE = 0;
  if (MODE == 1) {
    Meff = cnt[e];
    if (m0 >= Meff) return;
    baseE = ebase[e];
  }
  const float* BE = B + (long)e * estrideB;

  unsigned short* As = (unsigned short*)smem;   // [2][4096] ushorts
  float* BsF = (float*)(smem + 16384);          // [2][8192] floats

  const int lrow = lane >> 2;
  const int lcol = (((lane & 3) ^ ((lrow >> 1) & 3)) << 4);

  const char* aP[2];
#pragma unroll
  for (int i = 0; i < 2; ++i) {
    int m = m0 + wid * 32 + i * 16 + lrow;
    long arow;
    if (MODE == 1) {
      int mm = (m < Meff - 1) ? m : (Meff - 1);
      arow = baseE + mm;
    } else {
      arow = m;
    }
    aP[i] = (const char*)A + arow * (long)(Kstride * 2) + (long)kbeg * 2 + lcol;
  }

  const int br8 = lane >> 3;
  const int bck = (lane & 7) ^ (br8 & 7);
  const char* bPf[8];
#pragma unroll
  for (int i = 0; i < 8; ++i) {
    int n = n0 + wid * 64 + i * 8 + br8;
    bPf[i] = (const char*)BE + (long)n * (Kstride * 4) + (long)kbeg * 4 + bck * 16;
  }

  floatx4 acc[4][8];
  floatx4 zero = {0.f, 0.f, 0.f, 0.f};
#pragma unroll
  for (int i = 0; i < 4; ++i)
#pragma unroll
    for (int j = 0; j < 8; ++j) acc[i][j] = zero;

  const int ar = lane & 15;
  const int aksw = (((lane >> 4) ^ ((ar >> 1) & 3)) << 3);
  const int kk = lane >> 4;

  auto stage = [&](int p, int k0) {
#pragma unroll
    for (int i = 0; i < 2; ++i)
      gl_lds16(aP[i] + (long)k0 * 2, &As[p * ATILE + (wid * 32 + i * 16) * BK]);
#pragma unroll
    for (int i = 0; i < 8; ++i)
      gl_lds16(bPf[i] + (long)k0 * 4, &BsF[p * BTILEF + (wid * 64 + i * 8) * BK]);
  };

  stage(0, 0);
  const int NI = kcnt / BK;
  for (int i = 0; i < NI; ++i) {
    __syncthreads();
    if (i + 1 < NI) stage((i + 1) & 1, (i + 1) * BK);
    const unsigned short* Ab = &As[(i & 1) * ATILE];
    const float* Bb = &BsF[(i & 1) * BTILEF];
    short8 af[4], bf[8];
#pragma unroll
    for (int tm = 0; tm < 4; ++tm)
      af[tm] = *(const short8*)&Ab[(wm * 64 + tm * 16 + ar) * BK + aksw];
#pragma unroll
    for (int tn = 0; tn < 8; ++tn)
      bf[tn] = bfrag_f32(Bb, wn * 128 + tn * 16 + ar, kk);
#pragma unroll
    for (int tm = 0; tm < 4; ++tm)
#pragma unroll
      for (int tn = 0; tn < 8; ++tn)
        acc[tm][tn] = __builtin_amdgcn_mfma_f32_16x16x32_bf16(af[tm], bf[tn], acc[tm][tn], 0, 0, 0);
  }

#pragma unroll
  for (int tm = 0; tm < 4; ++tm)
#pragma unroll
    for (int r = 0; r < 4; ++r) {
      int row = m0 + wm * 64 + tm * 16 + (lane >> 4) * 4 + r;
      if (MODE == 1 && row >= Meff) continue;
      long orow = (MODE == 1) ? (long)(baseE + row) : (long)row;
#pragma unroll
      for (int tn = 0; tn < 8; ++tn) {
        int col = n0 + wn * 128 + tn * 16 + (lane & 15);
        float v = acc[tm][tn][r];
        if (MODE == 0) {
          OutF[orow * N + col] = v;
        } else {
          OutB[orow * N + col] = f2bf(v);
        }
      }
    }
}

// Fused launch (256 threads, 80KB LDS), r4-proven grid shape:
//   [0,128)   shared down split-K x2 (ks = bid>>6; 4bx x 16by, NI=32):
//             ks0 -> out raw fp32, ks1 -> spart bf16; B = shared_down fp32
//   [128,640) expert down (4bx x 16by per expert, NI=16); B = down_proj fp32
__global__ __launch_bounds__(256, 2) void down_fused(
    const unsigned short* __restrict__ act_s, const float* __restrict__ sdw,
    float* __restrict__ out, unsigned short* __restrict__ spart,
    const unsigned short* __restrict__ act_e, const float* __restrict__ dwn,
    unsigned short* __restrict__ eout, const int* __restrict__ ebase,
    const int* __restrict__ cnt) {
  __shared__ __align__(16) char smem[81920];
  int bid = blockIdx.x;
  if (bid < 128) {
    int ks = bid >> 6;
    int rem = bid & 63;  // bx in [0,4), by in [0,16)
    if (ks == 0)
      down_body<0>(smem, rem & 3, rem >> 2, 0, act_s, sdw, out, nullptr,
                   nullptr, nullptr, H_DIM, SI_DIM, 0, 1024, 0);
    else
      down_body<2>(smem, rem & 3, rem >> 2, 0, act_s, sdw, nullptr, spart,
                   nullptr, nullptr, H_DIM, SI_DIM, 1024, 1024, 0);
  } else {
    int b2 = bid - 128;
    int e = b2 >> 6;
    int rem = b2 & 63;  // bx in [0,4), by in [0,16)
    down_body<1>(smem, rem & 3, rem >> 2, e, act_e, dwn, nullptr, eout,
                 ebase, cnt, H_DIM, I_DIM, 0, I_DIM, (long)H_DIM * I_DIM);
  }
}

// ---------------------------------------------------------------------------
// Combine: out[t][h] = sg[t]*(p0 + p1) + w0*eout[s0][h] + w1*eout[s1][h].
// p0 = raw fp32 in out, p1 = bf16 in spart. One block per token.
// ---------------------------------------------------------------------------
__global__ __launch_bounds__(256) void combine_kernel(
    float* __restrict__ out, const unsigned short* __restrict__ spart,
    const unsigned short* __restrict__ eout, const float* __restrict__ sg,
    const float2* __restrict__ w01, const int* __restrict__ tok_slot) {
  int t = blockIdx.x;
  int c = threadIdx.x;  // 256 threads x 4 elems = 1024
  float sgr = sg[t];
  float2 wr = w01[t];
  int s0 = tok_slot[2 * t];
  int s1 = tok_slot[2 * t + 1];
  ushort4 p1 = ((const ushort4*)(spart + (long)t * H_DIM))[c];
  ushort4 e0 = ((const ushort4*)(eout + (long)s0 * H_DIM))[c];
  ushort4 e1 = ((const ushort4*)(eout + (long)s1 * H_DIM))[c];
  float4* op = &((float4*)(out + (long)t * H_DIM))[c];
  float4 o = *op;
  o.x = sgr * (o.x + bf2f(p1.x)) + wr.x * bf2f(e0.x) + wr.y * bf2f(e1.x);
  o.y = sgr * (o.y + bf2f(p1.y)) + wr.x * bf2f(e0.y) + wr.y * bf2f(e1.y);
  o.z = sgr * (o.z + bf2f(p1.z)) + wr.x * bf2f(e0.z) + wr.y * bf2f(e1.z);
  o.w = sgr * (o.w + bf2f(p1.w)) + wr.x * bf2f(e0.w) + wr.y * bf2f(e1.w);
  *op = o;
}

// ---------------------------------------------------------------------------
// Workspace map (bytes), total ~25.2 MB (weights no longer copied):
//   0         xb       bf16[2048][1024]   (reused as spart after swiglu)
//   4194304   act_s    bf16[2048][2048]
//  12582912   act_e    bf16[4096][512]
//  16777216   eout     bf16[4096][1024]
//  25165824   sg / top2 / w01 / cnt / ebase / slot_token / tok_slot
// ---------------------------------------------------------------------------
extern "C" void kernel_launch(void* const* d_in, const int* in_sizes, int n_in,
                              void* d_out, int out_size, void* d_ws, size_t ws_size,
                              hipStream_t stream) {
  const float* x = (const float*)d_in[0];
  const float* rw = (const float*)d_in[1];
  const float* gup = (const float*)d_in[2];
  const float* dwn = (const float*)d_in[3];
  const float* sgw = (const float*)d_in[4];
  const float* suw = (const float*)d_in[5];
  const float* sdw = (const float*)d_in[6];
  const float* segw = (const float*)d_in[7];
  float* out = (float*)d_out;

  char* w = (char*)d_ws;
  unsigned short* xb = (unsigned short*)(w + 0);
  unsigned short* act_s = (unsigned short*)(w + 4194304L);
  unsigned short* act_e = (unsigned short*)(w + 12582912L);
  unsigned short* eout = (unsigned short*)(w + 16777216L);
  float* sg = (float*)(w + 25165824L);
  int* top2 = (int*)(w + 25174016L);
  float2* w01 = (float2*)(w + 25182208L);
  int* cnt = (int*)(w + 25198592L);
  int* ebase = (int*)(w + 25198848L);
  int* slot_token = (int*)(w + 25199104L);
  int* tok_slot = (int*)(w + 25215488L);
  unsigned short* spart = xb;  // xb dead after swiglu_fused; reuse

  // router (512 blocks) + x cast (1024 blocks) — weights are NOT cast
  cast_router<<<1536, 256, 0, stream>>>(x, rw, segw, xb, top2, w01, sg);
  build_lists<<<E_NUM, 256, 0, stream>>>(top2, cnt, ebase, slot_token, tok_slot);
  // fused shared+expert SwiGLU; B-operands = fp32 weights (direct read)
  swiglu_fused<<<768, 256, 0, stream>>>(xb, sgw, suw, act_s, gup, act_e,
                                        slot_token, cnt, ebase);
  // fused shared (split-K x2) + expert down-proj; B = fp32 weights
  down_fused<<<640, 256, 0, stream>>>(act_s, sdw, out, spart, act_e, dwn,
                                      eout, ebase, cnt);
  // out = sg*(p0+p1) + w0*eout[s0] + w1*eout[s1]
  combine_kernel<<<T_TOK, 256, 0, stream>>>(out, spart, eout, sg, w01, tok_slot);
}

// Round 10
// 196.275 us; speedup vs baseline: 1.0584x; 1.0584x over previous
//
#include <hip/hip_runtime.h>

// Problem constants (B=2,S=1024 -> T=2048; H=1024, I=512, SI=2048, E=8, TOPK=2)
#define T_TOK 2048
#define H_DIM 1024
#define I_DIM 512
#define SI_DIM 2048
#define E_NUM 8
#define NSLOT 4096  // total expert slots: exactly 2 per token

typedef __attribute__((ext_vector_type(8))) short short8;   // 8 x bf16 (4 VGPRs)
typedef __attribute__((ext_vector_type(4))) float floatx4;  // MFMA C/D

// fp32 -> bf16 round-to-nearest-even
__device__ inline unsigned short f2bf(float f) {
  unsigned u = __builtin_bit_cast(unsigned, f);
  u = (u + 0x7FFFu + ((u >> 16) & 1u)) >> 16;
  return (unsigned short)u;
}
__device__ inline float bf2f(unsigned short u) {
  return __builtin_bit_cast(float, (unsigned)u << 16);
}

// async global->LDS, 16B per lane; LDS dest = wave-uniform base + lane*16
__device__ inline void gl_lds16(const void* g, void* l) {
  __builtin_amdgcn_global_load_lds(
      (const __attribute__((address_space(1))) unsigned int*)g,
      (__attribute__((address_space(3))) unsigned int*)l, 16, 0, 0);
}

// ---------------------------------------------------------------------------
// Fused cast + router. Blocks [0,512): router. [512,10752): cast of all six
// fp32 tensors -> bf16, 8 elems/thread, 16B stores (round-4 win).
// (Round-9 fp32-direct-weight experiment REVERTED: fp32 LDS rows are 128B =
// exactly 32 banks, so row index contributes nothing to bank index -> 3.2M
// bank conflicts + doubled staging issues; swiglu 42.5->77.4us.)
// ---------------------------------------------------------------------------
__global__ __launch_bounds__(256) void cast_router(
    const float* __restrict__ x, const float* __restrict__ rw,
    const float* __restrict__ segw,
    const float* __restrict__ s1, const float* __restrict__ s2,
    const float* __restrict__ s3, const float* __restrict__ s4,
    const float* __restrict__ s5,
    unsigned short* __restrict__ d0, unsigned short* __restrict__ d1,
    unsigned short* __restrict__ d2, unsigned short* __restrict__ d3,
    unsigned short* __restrict__ d4, unsigned short* __restrict__ d5,
    int* __restrict__ top2, float2* __restrict__ w01, float* __restrict__ sg) {
  const int bid = blockIdx.x;
  if (bid < 512) {
    // ---- router: one wave per token, fp32 logits (matches ref numerics) ----
    int t = bid * 4 + (threadIdx.x >> 6);
    int lane = threadIdx.x & 63;
    const float* xt = x + (long)t * H_DIM;
    float xv[16];
#pragma unroll
    for (int j = 0; j < 16; ++j) xv[j] = xt[j * 64 + lane];
    float dots[9];
#pragma unroll
    for (int e = 0; e < 8; ++e) {
      const float* w = rw + e * H_DIM;
      float s = 0.f;
#pragma unroll
      for (int j = 0; j < 16; ++j) s += xv[j] * w[j * 64 + lane];
      dots[e] = s;
    }
    {
      float s = 0.f;
#pragma unroll
      for (int j = 0; j < 16; ++j) s += xv[j] * segw[j * 64 + lane];
      dots[8] = s;
    }
#pragma unroll
    for (int off = 32; off > 0; off >>= 1) {
#pragma unroll
      for (int e = 0; e < 9; ++e) dots[e] += __shfl_xor(dots[e], off, 64);
    }
    if (lane == 0) {
      int e0 = 0;
      for (int e = 1; e < 8; ++e)
        if (dots[e] > dots[e0]) e0 = e;
      int e1 = (e0 == 0) ? 1 : 0;
      for (int e = 0; e < 8; ++e)
        if (e != e0 && dots[e] > dots[e1]) e1 = e;
      float p1 = expf(dots[e1] - dots[e0]);
      top2[t] = e0 | (e1 << 8);
      w01[t] = make_float2(1.f / (1.f + p1), p1 / (1.f + p1));
      sg[t] = 1.f / (1.f + expf(-dots[8]));
    }
  } else {
    // ---- cast: group = 8 fp32 elems -> 8 bf16 (one 16B store) ----
    long g = (long)(bid - 512) * 256 + threadIdx.x;  // group index, < 2621440
    const float* s;
    unsigned short* d;
    long off;
    if (g < 262144L)        { s = x;  d = d0; off = g; }             // x (2M elems)
    else if (g < 1310720L)  { s = s1; d = d1; off = g - 262144L; }   // gate_up (8.39M)
    else if (g < 1835008L)  { s = s2; d = d2; off = g - 1310720L; }  // down (4.19M)
    else if (g < 2097152L)  { s = s3; d = d3; off = g - 1835008L; }  // shared_gate (2M)
    else if (g < 2359296L)  { s = s4; d = d4; off = g - 2097152L; }  // shared_up (2M)
    else                    { s = s5; d = d5; off = g - 2359296L; }  // shared_down (2M)
    const float4* sp = (const float4*)s;
    float4 v0 = sp[off * 2];
    float4 v1 = sp[off * 2 + 1];
    uint4 u;
    u.x = (unsigned)f2bf(v0.x) | ((unsigned)f2bf(v0.y) << 16);
    u.y = (unsigned)f2bf(v0.z) | ((unsigned)f2bf(v0.w) << 16);
    u.z = (unsigned)f2bf(v1.x) | ((unsigned)f2bf(v1.y) << 16);
    u.w = (unsigned)f2bf(v1.z) | ((unsigned)f2bf(v1.w) << 16);
    ((uint4*)d)[off] = u;
  }
}

// ---------------------------------------------------------------------------
// Router phase 2: one block per expert; block-wide scan -> compact slot list
// (global base = #assignments to experts < e) + tok_slot back-pointers.
// ---------------------------------------------------------------------------
__global__ __launch_bounds__(256) void build_lists(
    const int* __restrict__ top2, int* __restrict__ cnt, int* __restrict__ ebase,
    int* __restrict__ slot_token, int* __restrict__ tok_slot) {
  const int e = blockIdx.x;
  const int tid = threadIdx.x;
  const int lane = tid & 63, wid = tid >> 6;
  __shared__ int wsum[4], wbelow[4];
  const int base_t = tid * 8;  // 2048 / 256
  int mk[8], kk[8];
  int c = 0, below = 0;
#pragma unroll
  for (int j = 0; j < 8; ++j) {
    int p = top2[base_t + j];
    int e0 = p & 0xFF, e1 = (p >> 8) & 0xFF;
    below += (e0 < e) + (e1 < e);
    int m = 0, k = 0;
    if (e0 == e) { m = 1; k = 0; }
    else if (e1 == e) { m = 1; k = 1; }
    mk[j] = m; kk[j] = k;
    c += m;
  }
  int inc = c;
#pragma unroll
  for (int off = 1; off < 64; off <<= 1) {
    int n = __shfl_up(inc, off, 64);
    if (lane >= off) inc += n;
  }
  int bsum = below;
#pragma unroll
  for (int off = 32; off > 0; off >>= 1) bsum += __shfl_xor(bsum, off, 64);
  if (lane == 63) wsum[wid] = inc;
  if (lane == 0) wbelow[wid] = bsum;
  __syncthreads();
  int woff = 0;
#pragma unroll
  for (int i = 0; i < 4; ++i)
    if (i < wid) woff += wsum[i];
  int baseE = wbelow[0] + wbelow[1] + wbelow[2] + wbelow[3];
  int pos = baseE + woff + inc - c;
#pragma unroll
  for (int j = 0; j < 8; ++j) {
    if (mk[j]) {
      slot_token[pos] = base_t + j;
      tok_slot[2 * (base_t + j) + kk[j]] = pos;
      pos++;
    }
  }
  if (tid == 255) cnt[e] = woff + inc;
  if (tid == 0) ebase[e] = baseE;
}

// ---------------------------------------------------------------------------
// Fused SwiGLU GEMM body: act = silu(A@Bg^T)*(A@Bu^T), bf16, fp32 acc.
// BM=128, BN=128, BK=32, 256 threads = 4 waves (2m x 2n); 32 MFMA/wave-iter.
// Round-4 proven loop: double-buffered LDS (1 barrier/iter) + XOR swizzle
// (0 conflicts). This is the measured optimum of the 2-barrier structure.
// ---------------------------------------------------------------------------
template <bool GATHER>
__device__ __forceinline__ void swiglu_body(
    char* smem, int bx, int by, int e,
    const unsigned short* __restrict__ A, const unsigned short* __restrict__ Bg,
    const unsigned short* __restrict__ Bu, unsigned short* __restrict__ Out,
    const int* __restrict__ slot_token, const int* __restrict__ cnt,
    const int* __restrict__ ebase, int N, int K, long estrideB) {
  constexpr int BM = 128, BN = 128, BK = 32;
  constexpr int ATILE = BM * BK;
  constexpr int BTILE = BN * BK;
  const int tid = threadIdx.x;
  const int lane = tid & 63;
  const int wid = tid >> 6;  // 0..3
  const int wm = wid & 1;
  const int wn = wid >> 1;
  const int m0 = by * BM;
  const int n0 = bx * BN;
  int Meff = 0, baseE = 0;
  if (GATHER) {
    Meff = cnt[e];
    if (m0 >= Meff) return;
    baseE = ebase[e];
  }
  const unsigned short* BgE = Bg + (long)e * estrideB;
  const unsigned short* BuE = Bu + (long)e * estrideB;

  unsigned short* As = (unsigned short*)smem;  // [2][128*32]
  unsigned short* Bgs = As + 2 * ATILE;        // [2][128*32]
  unsigned short* Bus = Bgs + 2 * BTILE;       // [2][128*32]

  const int lrow = lane >> 2;  // 16 rows / 1KB chunk
  const int lcol = (((lane & 3) ^ ((lrow >> 1) & 3)) << 4);  // swizzled 16B col

  const char* aP[2];
  const char* bgP[2];
  const char* buP[2];
#pragma unroll
  for (int i = 0; i < 2; ++i) {
    int m = m0 + wid * 32 + i * 16 + lrow;
    long row;
    if (GATHER) {
      int mm = (m < Meff - 1) ? m : (Meff - 1);  // clamp tail to valid slot
      row = slot_token[baseE + mm];
    } else {
      row = m;
    }
    aP[i] = (const char*)A + row * (long)(K * 2) + lcol;
    int n = n0 + wid * 32 + i * 16 + lrow;
    bgP[i] = (const char*)BgE + (long)n * (K * 2) + lcol;
    buP[i] = (const char*)BuE + (long)n * (K * 2) + lcol;
  }

  floatx4 accG[4][4], accU[4][4];
  floatx4 zero = {0.f, 0.f, 0.f, 0.f};
#pragma unroll
  for (int i = 0; i < 4; ++i)
#pragma unroll
    for (int j = 0; j < 4; ++j) { accG[i][j] = zero; accU[i][j] = zero; }

  const int ar = lane & 15;
  const int aksw = (((lane >> 4) ^ ((ar >> 1) & 3)) << 3);  // swizzled k-chunk

  auto stage = [&](int p, int k0) {
#pragma unroll
    for (int i = 0; i < 2; ++i) {
      gl_lds16(aP[i] + (long)k0 * 2, &As[p * ATILE + (wid * 32 + i * 16) * BK]);
      gl_lds16(bgP[i] + (long)k0 * 2, &Bgs[p * BTILE + (wid * 32 + i * 16) * BK]);
      gl_lds16(buP[i] + (long)k0 * 2, &Bus[p * BTILE + (wid * 32 + i * 16) * BK]);
    }
  };

  stage(0, 0);
  const int NI = K / BK;
  for (int i = 0; i < NI; ++i) {
    __syncthreads();  // vmcnt drained before barrier -> buf[i&1] ready
    if (i + 1 < NI) stage((i + 1) & 1, (i + 1) * BK);
    const unsigned short* Ab = &As[(i & 1) * ATILE];
    const unsigned short* Gb = &Bgs[(i & 1) * BTILE];
    const unsigned short* Ub = &Bus[(i & 1) * BTILE];
    short8 af[4], bgf[4], buf2[4];
#pragma unroll
    for (int tm = 0; tm < 4; ++tm)
      af[tm] = *(const short8*)&Ab[(wm * 64 + tm * 16 + ar) * BK + aksw];
#pragma unroll
    for (int tn = 0; tn < 4; ++tn) {
      bgf[tn] = *(const short8*)&Gb[(wn * 64 + tn * 16 + ar) * BK + aksw];
      buf2[tn] = *(const short8*)&Ub[(wn * 64 + tn * 16 + ar) * BK + aksw];
    }
#pragma unroll
    for (int tm = 0; tm < 4; ++tm)
#pragma unroll
      for (int tn = 0; tn < 4; ++tn) {
        accG[tm][tn] = __builtin_amdgcn_mfma_f32_16x16x32_bf16(af[tm], bgf[tn], accG[tm][tn], 0, 0, 0);
        accU[tm][tn] = __builtin_amdgcn_mfma_f32_16x16x32_bf16(af[tm], buf2[tn], accU[tm][tn], 0, 0, 0);
      }
  }

#pragma unroll
  for (int tm = 0; tm < 4; ++tm)
#pragma unroll
    for (int tn = 0; tn < 4; ++tn)
#pragma unroll
      for (int r = 0; r < 4; ++r) {
        int row = m0 + wm * 64 + tm * 16 + (lane >> 4) * 4 + r;
        int col = n0 + wn * 64 + tn * 16 + (lane & 15);
        if (!GATHER || row < Meff) {
          float g = accG[tm][tn][r];
          float u = accU[tm][tn][r];
          float act = g / (1.f + expf(-g)) * u;
          Out[(long)(baseE + row) * N + col] = f2bf(act);
        }
      }
}

// Fused launch (256 threads):
//   [0,256)   shared SwiGLU (BM128xBN128: 16bx x 16by)
//   [256,768) expert SwiGLU (4bx x 16by per expert, ~128 active)
__global__ __launch_bounds__(256, 2) void swiglu_fused(
    const unsigned short* __restrict__ xb, const unsigned short* __restrict__ sgate,
    const unsigned short* __restrict__ sup, unsigned short* __restrict__ act_s,
    const unsigned short* __restrict__ gup, unsigned short* __restrict__ act_e,
    const int* __restrict__ slot_token, const int* __restrict__ cnt,
    const int* __restrict__ ebase) {
  __shared__ __align__(16) char smem[49152];
  int bid = blockIdx.x;
  if (bid < 256) {
    swiglu_body<false>(smem, bid & 15, bid >> 4, 0, xb, sgate, sup, act_s,
                       nullptr, nullptr, nullptr, SI_DIM, H_DIM, 0);
  } else {
    int b2 = bid - 256;
    int e = b2 >> 6;
    int rem = b2 & 63;  // bx in [0,4), by in [0,16)
    swiglu_body<true>(smem, rem & 3, rem >> 2, e, xb, gup,
                      gup + (long)I_DIM * H_DIM, act_e, slot_token, cnt,
                      ebase, I_DIM, H_DIM, (long)2 * I_DIM * H_DIM);
  }
}

// ---------------------------------------------------------------------------
// Down-proj GEMM body: C = A@B^T. BM=128, BN=256, BK=32, 4 waves,
// 32 MFMA/wave-iter, round-4 proven dbuf loop + XOR swizzle.
// MODE 0: shared split-K part 0 -> OutF[row][col] = v (raw fp32)
// MODE 2: shared split-K part 1 -> OutB[row][col] = bf16(v)
// MODE 1: expert -> OutB[(baseE+row)][col] = bf16(v)
// ---------------------------------------------------------------------------
template <int MODE>
__device__ __forceinline__ void down_body(
    char* smem, int bx, int by, int e,
    const unsigned short* __restrict__ A, const unsigned short* __restrict__ B,
    float* __restrict__ OutF, unsigned short* __restrict__ OutB,
    const int* __restrict__ ebase, const int* __restrict__ cnt,
    int N, int Kstride, int kbeg, int kcnt, long estrideB) {
  constexpr int BM = 128, BN = 256, BK = 32;
  constexpr int ATILE = BM * BK;   // 4096 ushorts
  constexpr int BTILE = BN * BK;   // 8192 ushorts
  const int tid = threadIdx.x;
  const int lane = tid & 63;
  const int wid = tid >> 6;
  const int wm = wid & 1;
  const int wn = wid >> 1;
  const int m0 = by * BM;
  const int n0 = bx * BN;
  int Meff = 0, baseE = 0;
  if (MODE == 1) {
    Meff = cnt[e];
    if (m0 >= Meff) return;
    baseE = ebase[e];
  }
  const unsigned short* BE = B + (long)e * estrideB;

  unsigned short* As = (unsigned short*)smem;  // [2][128*32]
  unsigned short* Bs = As + 2 * ATILE;         // [2][256*32]

  const int lrow = lane >> 2;
  const int lcol = (((lane & 3) ^ ((lrow >> 1) & 3)) << 4);

  const char* aP[2];
  const char* bP[4];
#pragma unroll
  for (int i = 0; i < 2; ++i) {
    int m = m0 + wid * 32 + i * 16 + lrow;
    long arow;
    if (MODE == 1) {
      int mm = (m < Meff - 1) ? m : (Meff - 1);
      arow = baseE + mm;
    } else {
      arow = m;
    }
    aP[i] = (const char*)A + arow * (long)(Kstride * 2) + (long)kbeg * 2 + lcol;
  }
#pragma unroll
  for (int i = 0; i < 4; ++i) {
    int n = n0 + wid * 64 + i * 16 + lrow;
    bP[i] = (const char*)BE + (long)n * (Kstride * 2) + (long)kbeg * 2 + lcol;
  }

  floatx4 acc[4][8];
  floatx4 zero = {0.f, 0.f, 0.f, 0.f};
#pragma unroll
  for (int i = 0; i < 4; ++i)
#pragma unroll
    for (int j = 0; j < 8; ++j) acc[i][j] = zero;

  const int ar = lane & 15;
  const int aksw = (((lane >> 4) ^ ((ar >> 1) & 3)) << 3);

  auto stage = [&](int p, int k0) {
#pragma unroll
    for (int i = 0; i < 2; ++i)
      gl_lds16(aP[i] + (long)k0 * 2, &As[p * ATILE + (wid * 32 + i * 16) * BK]);
#pragma unroll
    for (int i = 0; i < 4; ++i)
      gl_lds16(bP[i] + (long)k0 * 2, &Bs[p * BTILE + (wid * 64 + i * 16) * BK]);
  };

  stage(0, 0);
  const int NI = kcnt / BK;
  for (int i = 0; i < NI; ++i) {
    __syncthreads();
    if (i + 1 < NI) stage((i + 1) & 1, (i + 1) * BK);
    const unsigned short* Ab = &As[(i & 1) * ATILE];
    const unsigned short* Bb = &Bs[(i & 1) * BTILE];
    short8 af[4], bf[8];
#pragma unroll
    for (int tm = 0; tm < 4; ++tm)
      af[tm] = *(const short8*)&Ab[(wm * 64 + tm * 16 + ar) * BK + aksw];
#pragma unroll
    for (int tn = 0; tn < 8; ++tn)
      bf[tn] = *(const short8*)&Bb[(wn * 128 + tn * 16 + ar) * BK + aksw];
#pragma unroll
    for (int tm = 0; tm < 4; ++tm)
#pragma unroll
      for (int tn = 0; tn < 8; ++tn)
        acc[tm][tn] = __builtin_amdgcn_mfma_f32_16x16x32_bf16(af[tm], bf[tn], acc[tm][tn], 0, 0, 0);
  }

#pragma unroll
  for (int tm = 0; tm < 4; ++tm)
#pragma unroll
    for (int r = 0; r < 4; ++r) {
      int row = m0 + wm * 64 + tm * 16 + (lane >> 4) * 4 + r;
      if (MODE == 1 && row >= Meff) continue;
      long orow = (MODE == 1) ? (long)(baseE + row) : (long)row;
#pragma unroll
      for (int tn = 0; tn < 8; ++tn) {
        int col = n0 + wn * 128 + tn * 16 + (lane & 15);
        float v = acc[tm][tn][r];
        if (MODE == 0) {
          OutF[orow * N + col] = v;
        } else {
          OutB[orow * N + col] = f2bf(v);
        }
      }
    }
}

// Fused launch (256 threads):
//   [0,128)   shared down split-K (ks = bid>>6; 4bx x 16by):
//             ks0 -> out raw fp32, ks1 -> spart bf16 (NI=32 each)
//   [128,640) expert down (4bx x 16by per expert; ~256 active, NI=16)
__global__ __launch_bounds__(256, 2) void down_fused(
    const unsigned short* __restrict__ act_s, const unsigned short* __restrict__ sdown,
    float* __restrict__ out, unsigned short* __restrict__ spart,
    const unsigned short* __restrict__ act_e, const unsigned short* __restrict__ downw,
    unsigned short* __restrict__ eout, const int* __restrict__ ebase,
    const int* __restrict__ cnt) {
  __shared__ __align__(16) char smem[49152];
  int bid = blockIdx.x;
  if (bid < 128) {
    int ks = bid >> 6;
    int rem = bid & 63;  // bx in [0,4), by in [0,16)
    if (ks == 0)
      down_body<0>(smem, rem & 3, rem >> 2, 0, act_s, sdown, out, nullptr,
                   nullptr, nullptr, H_DIM, SI_DIM, 0, 1024, 0);
    else
      down_body<2>(smem, rem & 3, rem >> 2, 0, act_s, sdown, nullptr, spart,
                   nullptr, nullptr, H_DIM, SI_DIM, 1024, 1024, 0);
  } else {
    int b2 = bid - 128;
    int e = b2 >> 6;
    int rem = b2 & 63;  // bx in [0,4), by in [0,16)
    down_body<1>(smem, rem & 3, rem >> 2, e, act_e, downw, nullptr, eout,
                 ebase, cnt, H_DIM, I_DIM, 0, I_DIM, (long)H_DIM * I_DIM);
  }
}

// ---------------------------------------------------------------------------
// Combine: out[t][h] = sg[t]*(p0 + p1) + w0*eout[s0][h] + w1*eout[s1][h].
// p0 = raw fp32 in out, p1 = bf16 in spart. One block per token.
// ---------------------------------------------------------------------------
__global__ __launch_bounds__(256) void combine_kernel(
    float* __restrict__ out, const unsigned short* __restrict__ spart,
    const unsigned short* __restrict__ eout, const float* __restrict__ sg,
    const float2* __restrict__ w01, const int* __restrict__ tok_slot) {
  int t = blockIdx.x;
  int c = threadIdx.x;  // 256 threads x 4 elems = 1024
  float sgr = sg[t];
  float2 wr = w01[t];
  int s0 = tok_slot[2 * t];
  int s1 = tok_slot[2 * t + 1];
  ushort4 p1 = ((const ushort4*)(spart + (long)t * H_DIM))[c];
  ushort4 e0 = ((const ushort4*)(eout + (long)s0 * H_DIM))[c];
  ushort4 e1 = ((const ushort4*)(eout + (long)s1 * H_DIM))[c];
  float4* op = &((float4*)(out + (long)t * H_DIM))[c];
  float4 o = *op;
  o.x = sgr * (o.x + bf2f(p1.x)) + wr.x * bf2f(e0.x) + wr.y * bf2f(e1.x);
  o.y = sgr * (o.y + bf2f(p1.y)) + wr.x * bf2f(e0.y) + wr.y * bf2f(e1.y);
  o.z = sgr * (o.z + bf2f(p1.z)) + wr.x * bf2f(e0.z) + wr.y * bf2f(e1.z);
  o.w = sgr * (o.w + bf2f(p1.w)) + wr.x * bf2f(e0.w) + wr.y * bf2f(e1.w);
  *op = o;
}

// ---------------------------------------------------------------------------
// Workspace map (bytes), total ~63.0 MB:
//   0         xb       bf16[2048][1024]     (reused as spart by down split-K)
//   4194304   gup_b    bf16[8][1024][1024]
//  20971520   down_b   bf16[8][1024][512]
//  29360128   sgate_b  bf16[2048][1024]
//  33554432   sup_b    bf16[2048][1024]
//  37748736   sdown_b  bf16[1024][2048]
//  41943040   act_s    bf16[2048][2048]
//  50331648   act_e    bf16[4096][512]
//  54525952   eout     bf16[4096][1024]
//  62914560   sg / top2 / w01 / cnt / ebase / slot_token / tok_slot
// ---------------------------------------------------------------------------
extern "C" void kernel_launch(void* const* d_in, const int* in_sizes, int n_in,
                              void* d_out, int out_size, void* d_ws, size_t ws_size,
                              hipStream_t stream) {
  const float* x = (const float*)d_in[0];
  const float* rw = (const float*)d_in[1];
  const float* gup = (const float*)d_in[2];
  const float* dwn = (const float*)d_in[3];
  const float* sgw = (const float*)d_in[4];
  const float* suw = (const float*)d_in[5];
  const float* sdw = (const float*)d_in[6];
  const float* segw = (const float*)d_in[7];
  float* out = (float*)d_out;

  char* w = (char*)d_ws;
  unsigned short* xb = (unsigned short*)(w + 0);
  unsigned short* gup_b = (unsigned short*)(w + 4194304L);
  unsigned short* down_b = (unsigned short*)(w + 20971520L);
  unsigned short* sgate_b = (unsigned short*)(w + 29360128L);
  unsigned short* sup_b = (unsigned short*)(w + 33554432L);
  unsigned short* sdown_b = (unsigned short*)(w + 37748736L);
  unsigned short* act_s = (unsigned short*)(w + 41943040L);
  unsigned short* act_e = (unsigned short*)(w + 50331648L);
  unsigned short* eout = (unsigned short*)(w + 54525952L);
  float* sg = (float*)(w + 62914560L);
  int* top2 = (int*)(w + 62922752L);
  float2* w01 = (float2*)(w + 62930944L);
  int* cnt = (int*)(w + 62947328L);
  int* ebase = (int*)(w + 62947584L);
  int* slot_token = (int*)(w + 62947840L);
  int* tok_slot = (int*)(w + 62964224L);
  unsigned short* spart = xb;  // xb dead after swiglu_fused; reuse for split-K partial

  // router (512 blocks, first) + cast of all six tensors (10240 blocks, 16B stores)
  cast_router<<<10752, 256, 0, stream>>>(x, rw, segw, gup, dwn, sgw, suw, sdw,
                                         xb, gup_b, down_b, sgate_b, sup_b,
                                         sdown_b, top2, w01, sg);
  build_lists<<<E_NUM, 256, 0, stream>>>(top2, cnt, ebase, slot_token, tok_slot);
  // fused shared+expert SwiGLU (~384 active = single generation)
  swiglu_fused<<<768, 256, 0, stream>>>(xb, sgate_b, sup_b, act_s, gup_b,
                                        act_e, slot_token, cnt, ebase);
  // fused shared (split-K x2) + expert down-proj, BN=256 (~384 active)
  down_fused<<<640, 256, 0, stream>>>(act_s, sdown_b, out, spart, act_e,
                                      down_b, eout, ebase, cnt);
  // out = sg*(p0+p1) + w0*eout[s0] + w1*eout[s1]
  combine_kernel<<<T_TOK, 256, 0, stream>>>(out, spart, eout, sg, w01, tok_slot);
}